// Round 6
// baseline (561.246 us; speedup 1.0000x reference)
//
#include <hip/hip_runtime.h>
#include <utility>

#define LMAX 8
#define NENT 249
#define NPAIR 45
#define EPB 128            // batch elements per block (2 per lane, f32x2-packed)
#define TPB 512            // 8 waves
#define ESTR 130           // padded elem stride (floats)
#define NCO 45             // sum_{l<=8}(l+1)
#define PLANE (NCO*ESTR)
#define P1END 30           // pairs [0,30) have l1<=3  -> FULL ranks [0,100)
#define FSPLIT 100         // FULL-rank phase split
#define PSLOT 115          // POWER slots base (phase-2 FULL uses slots [0,115))
#define NSLOT 149          // total stage slots

typedef __attribute__((ext_vector_type(2))) float f32x2;

struct P2 { int l1, l2; };

__host__ __device__ constexpr int tri_(int l){ return l*(l+1)/2; }
// F_l^{m} for m<0 equals (sr*Re, sq*Im) of the stored value at |m| (m>=1 only;
// m=0 is a full complex value — NO reality constraint).
__host__ __device__ constexpr int sr_(int m){ return m>=0 ? 1 : (((-m)&1)? -1 : 1); }
__host__ __device__ constexpr int sq_(int m){ return m>=0 ? 1 : (((-m)&1)? 1 : -1); }

__host__ __device__ constexpr P2 pair_of(int w){
  int n=0;
  for(int a=0;a<=LMAX;a++) for(int b=a;b<=LMAX;b++){ if(n==w) return P2{a,b}; n++; }
  return P2{0,0};
}

// index of (l1,l2,lo) in FULL_MAP generation order
__host__ __device__ constexpr int full_rank(int l1,int l2,int lo){
  int r=0;
  for(int a=0;a<=LMAX;a++) for(int b=a;b<=LMAX;b++){
    int hi=a+b>LMAX?LMAX:a+b;
    for(int c=b-a;c<=hi;c++){ if(a==l1&&b==l2&&c==lo) return r; r++; }
  }
  return -1;
}

// index of (l1,l2,lo) in POWER_MAP generation order; -1 if not a POWER entry
__host__ __device__ constexpr int power_idx(int l1,int l2,int lo){
  int n=0;
  for(int b=2;b<=LMAX;b++){
    if(l1==1&&l2==b&&lo==b-1) return n; n++;
    if(b>=4){ if(l1==1&&l2==b&&lo==b) return n; n++; }
  }
  for(int b=3;b<=LMAX;b++){
    if(l1==2&&l2==b&&lo==b-2) return n; n++;
    if(l1==2&&l2==b&&lo==b-1) return n; n++;
  }
  if(l1==3&&l2==3&&lo==2) return n; n++;
  for(int b=4;b<=LMAX;b++){
    if(l1==3&&l2==b&&lo==b-3) return n; n++;
    if((b&1)&&b>=5){
      if(l1==3&&l2==b&&lo==b-2) return n; n++;
      if(l1==3&&l2==b&&lo==b-1) return n; n++;
    }
  }
  return -1;
}

// ---- compile-time Clebsch-Gordan -------------------------------------------
__host__ __device__ constexpr double csqrt_(double x){
  if (x<=0.0) return 0.0;
  double v=x, s=1.0;
  while (v>4.0){ v*=0.25; s*=2.0; }
  while (v<0.25){ v*=4.0; s*=0.5; }
  double g=v;
  for(int i=0;i<48;i++) g=0.5*(g+v/g);
  return g*s;
}
__host__ __device__ constexpr double cgC(int j1,int m1,int j2,int m2,int j3,int m3){
  if (m1+m2 != m3) return 0.0;
  int dj=j1-j2; if(dj<0)dj=-dj;
  if (j3<dj || j3>j1+j2) return 0.0;
  if (m2<-j2 || m2>j2 || m1<-j1 || m1>j1 || m3<-j3 || m3>j3) return 0.0;
  double f[26]={}; f[0]=1.0;
  for(int t=1;t<26;t++) f[t]=f[t-1]*(double)t;
  double pre = csqrt_((2.0*j3+1.0)*f[j1+j2-j3]*f[j1-j2+j3]*f[-j1+j2+j3]/f[j1+j2+j3+1]);
  pre *= csqrt_(f[j1+m1]*f[j1-m1]*f[j2+m2]*f[j2-m2]*f[j3+m3]*f[j3-m3]);
  int kmin=0; if(j2-j3-m1>kmin)kmin=j2-j3-m1; if(j1-j3+m2>kmin)kmin=j1-j3+m2;
  int kmax=j1+j2-j3; if(j1-m1<kmax)kmax=j1-m1; if(j2+m2<kmax)kmax=j2+m2;
  double s=0.0;
  for(int k=kmin;k<=kmax;k++){
    double term = 1.0/(f[k]*f[j1+j2-j3-k]*f[j1-m1-k]*f[j2+m2-k]*f[j3-j2+m1+k]*f[j3-j1-m2+k]);
    s += (k&1)? -term : term;
  }
  return pre*s;
}

template<int L1,int L2>
struct CGTab {
  static constexpr int LOmx = (L1+L2<LMAX)?(L1+L2):LMAX;
  static constexpr int LOmn = L2-L1;
  static constexpr int NLO  = LOmx-LOmn+1;
  float c[NLO][2*LOmx+1][2*L1+1];   // [lo-LOmn][M+LOmx][m1+L1]
};
template<int L1,int L2>
__host__ __device__ constexpr CGTab<L1,L2> make_cgtab(){
  CGTab<L1,L2> T{};
  for(int lo=T.LOmn; lo<=T.LOmx; lo++)
    for(int M=-T.LOmx; M<=T.LOmx; M++)
      for(int m1=-L1;m1<=L1;m1++){
        double v=0.0;
        if (M>=-lo && M<=lo){
          int m2=M-m1;
          if(m2>=-L2&&m2<=L2) v = cgC(L1,m1,L2,m2,lo,M);
        }
        T.c[lo-T.LOmn][M+T.LOmx][m1+L1] = (float)v;
      }
  return T;
}

// ---- per-pair compute (FULL M range, no symmetry assumptions) --------------
// For each M in [-LOmax, LOmax]: products P_i = F1_{m1}*F2_{M-m1} once, then
// per-lo constexpr-CG dot; beta += Re(G_M conj(F3_M)); power += |G_M|^2.
template<int PI>
__device__ __attribute__((always_inline)) inline void do_pair(
    const float* __restrict__ lds, float* __restrict__ stage, int lane2)
{
  constexpr P2 pe = pair_of(PI);
  constexpr int L1 = pe.l1, L2 = pe.l2;
  constexpr int LOmin = L2-L1;
  constexpr int LOmax = (L1+L2<LMAX)?(L1+L2):LMAX;
  constexpr int NLO = LOmax-LOmin+1;
  constexpr int B1 = tri_(L1), B2 = tri_(L2);
  constexpr auto tab = make_cgtab<L1,L2>();

  // register-cache raw F1, F2 (|m| values; signs folded at compile time below)
  f32x2 X1[L1+1], Y1[L1+1], X2[L2+1], Y2[L2+1];
#pragma unroll
  for (int a=0;a<=L1;a++){
    X1[a] = *(const f32x2*)&lds[(B1+a)*ESTR + lane2];
    Y1[a] = *(const f32x2*)&lds[PLANE + (B1+a)*ESTR + lane2];
  }
#pragma unroll
  for (int a=0;a<=L2;a++){
    X2[a] = *(const f32x2*)&lds[(B2+a)*ESTR + lane2];
    Y2[a] = *(const f32x2*)&lds[PLANE + (B2+a)*ESTR + lane2];
  }

  f32x2 bAcc[NLO], pAcc[NLO];
#pragma unroll
  for (int t=0;t<NLO;t++){ bAcc[t]=f32x2{0.f,0.f}; pAcc[t]=f32x2{0.f,0.f}; }

#pragma unroll
  for (int M=-LOmax; M<=LOmax; M++){
    const int m1lo = (M-L2 > -L1) ? (M-L2) : -L1;
    const int m1hi = (M+L2 <  L1) ? (M+L2) :  L1;
    f32x2 Prd[2*L1+1], Pid[2*L1+1];
#pragma unroll
    for (int m1=-L1; m1<=L1; m1++){
      if (m1<m1lo || m1>m1hi) continue;     // folds after unroll
      const int i  = m1-m1lo;
      const int m2 = M-m1;
      const int a1 = m1<0?-m1:m1, a2 = m2<0?-m2:m2;
      const int s1 = sr_(m1)*sr_(m2);
      const int s2 = -(sq_(m1)*sq_(m2));
      const int s3 = sr_(m1)*sq_(m2);
      const int s4 = sq_(m1)*sr_(m2);
      f32x2 t1 = (s1>0? X1[a1] : -X1[a1]) * X2[a2];
      Prd[i] = __builtin_elementwise_fma((s2>0? Y1[a1] : -Y1[a1]), Y2[a2], t1);
      f32x2 t2 = (s3>0? X1[a1] : -X1[a1]) * Y2[a2];
      Pid[i] = __builtin_elementwise_fma((s4>0? Y1[a1] : -Y1[a1]), X2[a2], t2);
    }
#pragma unroll
    for (int lo=LOmin; lo<=LOmax; lo++){
      if (lo < (M<0?-M:M)) continue;        // G_M only exists for |M|<=lo
      f32x2 Gr = {0.f,0.f}, Gi = {0.f,0.f};
#pragma unroll
      for (int m1=-L1; m1<=L1; m1++){
        if (m1<m1lo || m1>m1hi) continue;
        const int i = m1-m1lo;
        const float C = tab.c[lo-LOmin][M+LOmax][m1+L1];
        if (C != 0.f){
          f32x2 Cv = {C,C};
          Gr = __builtin_elementwise_fma(Cv, Prd[i], Gr);
          Gi = __builtin_elementwise_fma(Cv, Pid[i], Gi);
        }
      }
      // beta += Re(G_M * conj(F3_M)); F3_M = (sr*x3, sq*y3) with x3,y3 at |M|
      const int aM = M<0?-M:M;
      const int B3 = tri_(lo);
      f32x2 x3 = *(const f32x2*)&lds[(B3+aM)*ESTR + lane2];
      f32x2 y3 = *(const f32x2*)&lds[PLANE + (B3+aM)*ESTR + lane2];
      const int AL = sr_(M), BE = sq_(M);   // fold after unroll
      bAcc[lo-LOmin] = __builtin_elementwise_fma(Gr, (AL>0? x3 : -x3), bAcc[lo-LOmin]);
      bAcc[lo-LOmin] = __builtin_elementwise_fma(Gi, (BE>0? y3 : -y3), bAcc[lo-LOmin]);
      if (power_idx(L1,L2,lo) >= 0){        // compile-time condition
        pAcc[lo-LOmin] = __builtin_elementwise_fma(Gr, Gr, pAcc[lo-LOmin]);
        pAcc[lo-LOmin] = __builtin_elementwise_fma(Gi, Gi, pAcc[lo-LOmin]);
      }
    }
  }

  // emit to LDS stage ([slot][elem]); pair-disjoint slots, no races
#pragma unroll
  for (int lo=LOmin; lo<=LOmax; lo++){
    const int fr   = full_rank(L1,L2,lo);
    const int slot = fr<FSPLIT ? fr : fr-FSPLIT;   // phase-1 pairs all have fr<100
    *(f32x2*)&stage[slot*ESTR + lane2] = bAcc[lo-LOmin];
    const int pidx = power_idx(L1,L2,lo);
    if (pidx>=0)
      *(f32x2*)&stage[(PSLOT+pidx)*ESTR + lane2] = pAcc[lo-LOmin];
  }
}

template<int PI>
__device__ __attribute__((always_inline)) inline void pair_step(
    const float* __restrict__ lds, float* __restrict__ stage, int lane2, int s, int e_)
{
  if (PI>=s && PI<e_) do_pair<PI>(lds, stage, lane2);   // wave-uniform
}
template<int OFF, int... Ps>
__device__ __attribute__((always_inline)) inline void pair_range(
    std::integer_sequence<int,Ps...>,
    const float* __restrict__ lds, float* __restrict__ stage, int lane2, int s, int e_)
{
  (pair_step<OFF+Ps>(lds, stage, lane2, s, e_), ...);
}

struct Bnd { int e1[8]; int e2[8]; };

constexpr int LDS_FLOATS = 2*PLANE + NSLOT*ESTR;
constexpr int LDS_BYTES  = LDS_FLOATS*4;   // 124,280 B
static_assert(LDS_BYTES <= 160*1024, "LDS over 160KB");

// __launch_bounds__(TPB, 1): second arg is min BLOCKS/CU on this toolchain
// (empirical: (512,2)->128 VGPR, (1024,4)->64, (512)->128 — only the
// CUDA/blocks reading fits all three). 1 block x 8 waves / 4 SIMD = 2
// waves/EU -> 256-VGPR cap. LDS (124KB) limits to 1 block/CU anyway, so
// this costs zero occupancy and removes the spills that produced the
// 150-270MB excess FETCH/WRITE in rounds 0/4/5.
__global__ __launch_bounds__(TPB, 1) void main_kernel(
    const float* __restrict__ re, const float* __restrict__ im,
    float* __restrict__ out, Bnd bnd)
{
  extern __shared__ float lds[];
  float* stage = lds + 2*PLANE;
  const int gbase = blockIdx.x*EPB;

  // stage the m<=l triangle of 128 elements into [coeff][elem] planes
  for (int t=threadIdx.x; t<EPB*81; t+=TPB){
    float vr = re[(size_t)gbase*81 + t];
    float vi = im[(size_t)gbase*81 + t];
    int elem = t/81, x = t - elem*81;
    int l = x/9, m = x - l*9;
    if (m<=l){
      int off = tri_(l)+m;
      lds[off*ESTR+elem] = vr;
      lds[PLANE + off*ESTR+elem] = vi;
    }
  }
  __syncthreads();

  const int lane  = threadIdx.x & 63;
  const int wv    = __builtin_amdgcn_readfirstlane(threadIdx.x >> 6);
  const int lane2 = lane*2;
  const int s1 = (wv==0)? 0      : bnd.e1[wv-1];
  const int E1 = bnd.e1[wv];
  const int s2 = (wv==0)? P1END  : bnd.e2[wv-1];
  const int E2 = bnd.e2[wv];
  const long long obase = (long long)gbase*NENT;

  // phase 1: pairs with l1<=3 (FULL ranks [0,100) + all POWER slots)
  pair_range<0>(std::make_integer_sequence<int,P1END>{}, lds, stage, lane2, s1, E1);
  __syncthreads();

  // flush A: out entries [0,100) per element (coalesced 400B runs)
  for (int p=threadIdx.x; p<EPB*FSPLIT; p+=TPB){
    int elem = p/FSPLIT, o = p - elem*FSPLIT;
    out[obase + (long long)elem*NENT + o] = stage[o*ESTR + elem];
  }
  __syncthreads();

  // phase 2: pairs with l1>=4 (FULL ranks [100,215) -> slots [0,115))
  pair_range<P1END>(std::make_integer_sequence<int,NPAIR-P1END>{}, lds, stage, lane2, s2, E2);
  __syncthreads();

  // flush B: out entries [100,249) <- slots [0,149) (coalesced 596B runs)
  for (int p=threadIdx.x; p<EPB*NSLOT; p+=TPB){
    int elem = p/NSLOT, o = p - elem*NSLOT;
    out[obase + (long long)elem*NENT + FSPLIT + o] = stage[o*ESTR + elem];
  }
}

extern "C" void kernel_launch(void* const* d_in, const int* in_sizes, int n_in,
                              void* d_out, int out_size, void* d_ws, size_t ws_size,
                              hipStream_t stream) {
  const float* re = (const float*)d_in[0];
  const float* im = (const float*)d_in[1];
  float* out = (float*)d_out;
  const int batch = in_sizes[0] / 81;

  hipFuncSetAttribute((const void*)main_kernel,
                      hipFuncAttributeMaxDynamicSharedMemorySize, LDS_BYTES);

  // per-pair cost model (pk-ops) for the 8-way per-phase wave balance
  double w[NPAIR];
  for (int p=0;p<NPAIR;p++){
    P2 pe = pair_of(p);
    int L1=pe.l1, L2=pe.l2;
    int LOmx=(L1+L2<LMAX)?(L1+L2):LMAX, LOmn=L2-L1;
    double ww = 2.0*(L1+L2+2);
    for (int M=-LOmx;M<=LOmx;M++){
      int lo_ = (M-L2>-L1)?(M-L2):-L1, hi_ = (M+L2<L1)?(M+L2):L1;
      int dn = hi_-lo_+1;
      ww += 4.0*dn;
      int aM = M<0?-M:M;
      for (int lo=(LOmn>aM?LOmn:aM); lo<=LOmx; lo++)
        ww += 2.0*dn + 2.0 + (power_idx(L1,L2,lo)>=0 ? 2.0 : 0.0);
    }
    w[p]=ww;
  }
  Bnd bnd;
  {  // phase 1: pairs [0, P1END)
    double tot=0; for(int p=0;p<P1END;p++) tot+=w[p];
    double acc=0; int c=0;
    for(int p=0;p<P1END && c<7;p++){ acc+=w[p]; if(acc>=tot*(c+1)/8.0) bnd.e1[c++]=p+1; }
    while(c<7) bnd.e1[c++]=P1END;
    bnd.e1[7]=P1END;
  }
  {  // phase 2: pairs [P1END, NPAIR)
    double tot=0; for(int p=P1END;p<NPAIR;p++) tot+=w[p];
    double acc=0; int c=0;
    for(int p=P1END;p<NPAIR && c<7;p++){ acc+=w[p]; if(acc>=tot*(c+1)/8.0) bnd.e2[c++]=p+1; }
    while(c<7) bnd.e2[c++]=NPAIR;
    bnd.e2[7]=NPAIR;
  }

  main_kernel<<<batch/EPB, TPB, LDS_BYTES, stream>>>(re, im, out, bnd);
}

// Round 7
// 368.746 us; speedup vs baseline: 1.5220x; 1.5220x over previous
//
#include <hip/hip_runtime.h>
#include <utility>

#define LMAX 8
#define NENT 249
#define NPAIR 45
#define EPB 128            // batch elements per block (2 per lane, f32x2-packed)
#define TPB 512            // 8 waves
#define ESTR 130           // padded elem stride (floats)
#define NCO 45             // sum_{l<=8}(l+1)
#define PLANE (NCO*ESTR)
#define P1END 30           // pairs [0,30) have l1<=3  -> FULL ranks [0,100)
#define FSPLIT 100         // FULL-rank phase split
#define PSLOT 115          // POWER slots base (phase-2 FULL uses slots [0,115))
#define NSLOT 149          // total stage slots

typedef __attribute__((ext_vector_type(2))) float f32x2;

struct P2 { int l1, l2; };

__host__ __device__ constexpr int tri_(int l){ return l*(l+1)/2; }
// F_l^{m} for m<0 equals (sr*Re, sq*Im) of the stored value at |m| (m>=1 only;
// m=0 is a full complex value — NO reality constraint).
__host__ __device__ constexpr int sr_(int m){ return m>=0 ? 1 : (((-m)&1)? -1 : 1); }
__host__ __device__ constexpr int sq_(int m){ return m>=0 ? 1 : (((-m)&1)? 1 : -1); }

__host__ __device__ constexpr P2 pair_of(int w){
  int n=0;
  for(int a=0;a<=LMAX;a++) for(int b=a;b<=LMAX;b++){ if(n==w) return P2{a,b}; n++; }
  return P2{0,0};
}

// index of (l1,l2,lo) in FULL_MAP generation order
__host__ __device__ constexpr int full_rank(int l1,int l2,int lo){
  int r=0;
  for(int a=0;a<=LMAX;a++) for(int b=a;b<=LMAX;b++){
    int hi=a+b>LMAX?LMAX:a+b;
    for(int c=b-a;c<=hi;c++){ if(a==l1&&b==l2&&c==lo) return r; r++; }
  }
  return -1;
}

// index of (l1,l2,lo) in POWER_MAP generation order; -1 if not a POWER entry
__host__ __device__ constexpr int power_idx(int l1,int l2,int lo){
  int n=0;
  for(int b=2;b<=LMAX;b++){
    if(l1==1&&l2==b&&lo==b-1) return n; n++;
    if(b>=4){ if(l1==1&&l2==b&&lo==b) return n; n++; }
  }
  for(int b=3;b<=LMAX;b++){
    if(l1==2&&l2==b&&lo==b-2) return n; n++;
    if(l1==2&&l2==b&&lo==b-1) return n; n++;
  }
  if(l1==3&&l2==3&&lo==2) return n; n++;
  for(int b=4;b<=LMAX;b++){
    if(l1==3&&l2==b&&lo==b-3) return n; n++;
    if((b&1)&&b>=5){
      if(l1==3&&l2==b&&lo==b-2) return n; n++;
      if(l1==3&&l2==b&&lo==b-1) return n; n++;
    }
  }
  return -1;
}

// ---- compile-time Clebsch-Gordan -------------------------------------------
__host__ __device__ constexpr double csqrt_(double x){
  if (x<=0.0) return 0.0;
  double v=x, s=1.0;
  while (v>4.0){ v*=0.25; s*=2.0; }
  while (v<0.25){ v*=4.0; s*=0.5; }
  double g=v;
  for(int i=0;i<48;i++) g=0.5*(g+v/g);
  return g*s;
}
__host__ __device__ constexpr double cgC(int j1,int m1,int j2,int m2,int j3,int m3){
  if (m1+m2 != m3) return 0.0;
  int dj=j1-j2; if(dj<0)dj=-dj;
  if (j3<dj || j3>j1+j2) return 0.0;
  if (m2<-j2 || m2>j2 || m1<-j1 || m1>j1 || m3<-j3 || m3>j3) return 0.0;
  double f[26]={}; f[0]=1.0;
  for(int t=1;t<26;t++) f[t]=f[t-1]*(double)t;
  double pre = csqrt_((2.0*j3+1.0)*f[j1+j2-j3]*f[j1-j2+j3]*f[-j1+j2+j3]/f[j1+j2+j3+1]);
  pre *= csqrt_(f[j1+m1]*f[j1-m1]*f[j2+m2]*f[j2-m2]*f[j3+m3]*f[j3-m3]);
  int kmin=0; if(j2-j3-m1>kmin)kmin=j2-j3-m1; if(j1-j3+m2>kmin)kmin=j1-j3+m2;
  int kmax=j1+j2-j3; if(j1-m1<kmax)kmax=j1-m1; if(j2+m2<kmax)kmax=j2+m2;
  double s=0.0;
  for(int k=kmin;k<=kmax;k++){
    double term = 1.0/(f[k]*f[j1+j2-j3-k]*f[j1-m1-k]*f[j2+m2-k]*f[j3-j2+m1+k]*f[j3-j1-m2+k]);
    s += (k&1)? -term : term;
  }
  return pre*s;
}

template<int L1,int L2>
struct CGTab {
  static constexpr int LOmx = (L1+L2<LMAX)?(L1+L2):LMAX;
  static constexpr int LOmn = L2-L1;
  static constexpr int NLO  = LOmx-LOmn+1;
  float c[NLO][2*LOmx+1][2*L1+1];   // [lo-LOmn][M+LOmx][m1+L1]
};
template<int L1,int L2>
__host__ __device__ constexpr CGTab<L1,L2> make_cgtab(){
  CGTab<L1,L2> T{};
  for(int lo=T.LOmn; lo<=T.LOmx; lo++)
    for(int M=-T.LOmx; M<=T.LOmx; M++)
      for(int m1=-L1;m1<=L1;m1++){
        double v=0.0;
        if (M>=-lo && M<=lo){
          int m2=M-m1;
          if(m2>=-L2&&m2<=L2) v = cgC(L1,m1,L2,m2,lo,M);
        }
        T.c[lo-T.LOmn][M+T.LOmx][m1+L1] = (float)v;
      }
  return T;
}

// ---- per-pair compute (FULL M range, no symmetry assumptions) --------------
// For each M in [-LOmax, LOmax]: products P_i = F1_{m1}*F2_{M-m1} once, then
// per-lo constexpr-CG dot; beta += Re(G_M conj(F3_M)); power += |G_M|^2.
template<int PI>
__device__ __attribute__((always_inline)) inline void do_pair(
    const float* __restrict__ lds, float* __restrict__ stage, int lane2)
{
  constexpr P2 pe = pair_of(PI);
  constexpr int L1 = pe.l1, L2 = pe.l2;
  constexpr int LOmin = L2-L1;
  constexpr int LOmax = (L1+L2<LMAX)?(L1+L2):LMAX;
  constexpr int NLO = LOmax-LOmin+1;
  constexpr int B1 = tri_(L1), B2 = tri_(L2);
  constexpr auto tab = make_cgtab<L1,L2>();

  // register-cache raw F1, F2 (|m| values; signs folded at compile time below)
  f32x2 X1[L1+1], Y1[L1+1], X2[L2+1], Y2[L2+1];
#pragma unroll
  for (int a=0;a<=L1;a++){
    X1[a] = *(const f32x2*)&lds[(B1+a)*ESTR + lane2];
    Y1[a] = *(const f32x2*)&lds[PLANE + (B1+a)*ESTR + lane2];
  }
#pragma unroll
  for (int a=0;a<=L2;a++){
    X2[a] = *(const f32x2*)&lds[(B2+a)*ESTR + lane2];
    Y2[a] = *(const f32x2*)&lds[PLANE + (B2+a)*ESTR + lane2];
  }

  f32x2 bAcc[NLO], pAcc[NLO];
#pragma unroll
  for (int t=0;t<NLO;t++){ bAcc[t]=f32x2{0.f,0.f}; pAcc[t]=f32x2{0.f,0.f}; }

#pragma unroll
  for (int M=-LOmax; M<=LOmax; M++){
    const int m1lo = (M-L2 > -L1) ? (M-L2) : -L1;
    const int m1hi = (M+L2 <  L1) ? (M+L2) :  L1;
    f32x2 Prd[2*L1+1], Pid[2*L1+1];
#pragma unroll
    for (int m1=-L1; m1<=L1; m1++){
      if (m1<m1lo || m1>m1hi) continue;     // folds after unroll
      const int i  = m1-m1lo;
      const int m2 = M-m1;
      const int a1 = m1<0?-m1:m1, a2 = m2<0?-m2:m2;
      const int s1 = sr_(m1)*sr_(m2);
      const int s2 = -(sq_(m1)*sq_(m2));
      const int s3 = sr_(m1)*sq_(m2);
      const int s4 = sq_(m1)*sr_(m2);
      f32x2 t1 = (s1>0? X1[a1] : -X1[a1]) * X2[a2];
      Prd[i] = __builtin_elementwise_fma((s2>0? Y1[a1] : -Y1[a1]), Y2[a2], t1);
      f32x2 t2 = (s3>0? X1[a1] : -X1[a1]) * Y2[a2];
      Pid[i] = __builtin_elementwise_fma((s4>0? Y1[a1] : -Y1[a1]), X2[a2], t2);
    }
#pragma unroll
    for (int lo=LOmin; lo<=LOmax; lo++){
      if (lo < (M<0?-M:M)) continue;        // G_M only exists for |M|<=lo
      f32x2 Gr = {0.f,0.f}, Gi = {0.f,0.f};
#pragma unroll
      for (int m1=-L1; m1<=L1; m1++){
        if (m1<m1lo || m1>m1hi) continue;
        const int i = m1-m1lo;
        const float C = tab.c[lo-LOmin][M+LOmax][m1+L1];
        if (C != 0.f){
          f32x2 Cv = {C,C};
          Gr = __builtin_elementwise_fma(Cv, Prd[i], Gr);
          Gi = __builtin_elementwise_fma(Cv, Pid[i], Gi);
        }
      }
      // beta += Re(G_M * conj(F3_M)); F3_M = (sr*x3, sq*y3) with x3,y3 at |M|
      const int aM = M<0?-M:M;
      const int B3 = tri_(lo);
      f32x2 x3 = *(const f32x2*)&lds[(B3+aM)*ESTR + lane2];
      f32x2 y3 = *(const f32x2*)&lds[PLANE + (B3+aM)*ESTR + lane2];
      const int AL = sr_(M), BE = sq_(M);   // fold after unroll
      bAcc[lo-LOmin] = __builtin_elementwise_fma(Gr, (AL>0? x3 : -x3), bAcc[lo-LOmin]);
      bAcc[lo-LOmin] = __builtin_elementwise_fma(Gi, (BE>0? y3 : -y3), bAcc[lo-LOmin]);
      if (power_idx(L1,L2,lo) >= 0){        // compile-time condition
        pAcc[lo-LOmin] = __builtin_elementwise_fma(Gr, Gr, pAcc[lo-LOmin]);
        pAcc[lo-LOmin] = __builtin_elementwise_fma(Gi, Gi, pAcc[lo-LOmin]);
      }
    }
  }

  // emit to LDS stage ([slot][elem]); pair-disjoint slots, no races
#pragma unroll
  for (int lo=LOmin; lo<=LOmax; lo++){
    const int fr   = full_rank(L1,L2,lo);
    const int slot = fr<FSPLIT ? fr : fr-FSPLIT;   // phase-1 pairs all have fr<100
    *(f32x2*)&stage[slot*ESTR + lane2] = bAcc[lo-LOmin];
    const int pidx = power_idx(L1,L2,lo);
    if (pidx>=0)
      *(f32x2*)&stage[(PSLOT+pidx)*ESTR + lane2] = pAcc[lo-LOmin];
  }
}

template<int PI>
__device__ __attribute__((always_inline)) inline void pair_step(
    const float* __restrict__ lds, float* __restrict__ stage, int lane2, int s, int e_)
{
  if (PI>=s && PI<e_) do_pair<PI>(lds, stage, lane2);   // wave-uniform
}
template<int OFF, int... Ps>
__device__ __attribute__((always_inline)) inline void pair_range(
    std::integer_sequence<int,Ps...>,
    const float* __restrict__ lds, float* __restrict__ stage, int lane2, int s, int e_)
{
  (pair_step<OFF+Ps>(lds, stage, lane2, s, e_), ...);
}

struct Bnd { int e1[8]; int e2[8]; };

constexpr int LDS_FLOATS = 2*PLANE + NSLOT*ESTR;
constexpr int LDS_BYTES  = LDS_FLOATS*4;   // 124,280 B
static_assert(LDS_BYTES <= 160*1024, "LDS over 160KB");

// amdgpu_waves_per_eu(2,2): pins the allocator's occupancy TARGET (not just
// the floor) to 2 waves/EU -> 512/2 = 256-VGPR budget. Launch-bounds args
// only set the floor; with dynamic LDS the allocator kept targeting 4
// waves/EU and spilled ~50 regs of the heavy pair bodies (rounds 0/5/6:
// FETCH/WRITE 196/383 MB vs 45/65 ideal). LDS (124KB -> 1 block/CU = 2
// waves/EU) makes >2 waves physically impossible, so max=2 costs nothing.
__global__ void __launch_bounds__(TPB)
__attribute__((amdgpu_waves_per_eu(2, 2)))
main_kernel(
    const float* __restrict__ re, const float* __restrict__ im,
    float* __restrict__ out, Bnd bnd)
{
  extern __shared__ float lds[];
  float* stage = lds + 2*PLANE;
  const int gbase = blockIdx.x*EPB;

  // stage the m<=l triangle of 128 elements into [coeff][elem] planes
  for (int t=threadIdx.x; t<EPB*81; t+=TPB){
    float vr = re[(size_t)gbase*81 + t];
    float vi = im[(size_t)gbase*81 + t];
    int elem = t/81, x = t - elem*81;
    int l = x/9, m = x - l*9;
    if (m<=l){
      int off = tri_(l)+m;
      lds[off*ESTR+elem] = vr;
      lds[PLANE + off*ESTR+elem] = vi;
    }
  }
  __syncthreads();

  const int lane  = threadIdx.x & 63;
  const int wv    = __builtin_amdgcn_readfirstlane(threadIdx.x >> 6);
  const int lane2 = lane*2;
  const int s1 = (wv==0)? 0      : bnd.e1[wv-1];
  const int E1 = bnd.e1[wv];
  const int s2 = (wv==0)? P1END  : bnd.e2[wv-1];
  const int E2 = bnd.e2[wv];
  const long long obase = (long long)gbase*NENT;

  // phase 1: pairs with l1<=3 (FULL ranks [0,100) + all POWER slots)
  pair_range<0>(std::make_integer_sequence<int,P1END>{}, lds, stage, lane2, s1, E1);
  __syncthreads();

  // flush A: out entries [0,100) per element (coalesced 400B runs)
  for (int p=threadIdx.x; p<EPB*FSPLIT; p+=TPB){
    int elem = p/FSPLIT, o = p - elem*FSPLIT;
    out[obase + (long long)elem*NENT + o] = stage[o*ESTR + elem];
  }
  __syncthreads();

  // phase 2: pairs with l1>=4 (FULL ranks [100,215) -> slots [0,115))
  pair_range<P1END>(std::make_integer_sequence<int,NPAIR-P1END>{}, lds, stage, lane2, s2, E2);
  __syncthreads();

  // flush B: out entries [100,249) <- slots [0,149) (coalesced 596B runs)
  for (int p=threadIdx.x; p<EPB*NSLOT; p+=TPB){
    int elem = p/NSLOT, o = p - elem*NSLOT;
    out[obase + (long long)elem*NENT + FSPLIT + o] = stage[o*ESTR + elem];
  }
}

extern "C" void kernel_launch(void* const* d_in, const int* in_sizes, int n_in,
                              void* d_out, int out_size, void* d_ws, size_t ws_size,
                              hipStream_t stream) {
  const float* re = (const float*)d_in[0];
  const float* im = (const float*)d_in[1];
  float* out = (float*)d_out;
  const int batch = in_sizes[0] / 81;

  hipFuncSetAttribute((const void*)main_kernel,
                      hipFuncAttributeMaxDynamicSharedMemorySize, LDS_BYTES);

  // per-pair cost model (pk-ops) for the 8-way per-phase wave balance
  double w[NPAIR];
  for (int p=0;p<NPAIR;p++){
    P2 pe = pair_of(p);
    int L1=pe.l1, L2=pe.l2;
    int LOmx=(L1+L2<LMAX)?(L1+L2):LMAX, LOmn=L2-L1;
    double ww = 2.0*(L1+L2+2);
    for (int M=-LOmx;M<=LOmx;M++){
      int lo_ = (M-L2>-L1)?(M-L2):-L1, hi_ = (M+L2<L1)?(M+L2):L1;
      int dn = hi_-lo_+1;
      ww += 4.0*dn;
      int aM = M<0?-M:M;
      for (int lo=(LOmn>aM?LOmn:aM); lo<=LOmx; lo++)
        ww += 2.0*dn + 2.0 + (power_idx(L1,L2,lo)>=0 ? 2.0 : 0.0);
    }
    w[p]=ww;
  }
  Bnd bnd;
  {  // phase 1: pairs [0, P1END)
    double tot=0; for(int p=0;p<P1END;p++) tot+=w[p];
    double acc=0; int c=0;
    for(int p=0;p<P1END && c<7;p++){ acc+=w[p]; if(acc>=tot*(c+1)/8.0) bnd.e1[c++]=p+1; }
    while(c<7) bnd.e1[c++]=P1END;
    bnd.e1[7]=P1END;
  }
  {  // phase 2: pairs [P1END, NPAIR)
    double tot=0; for(int p=P1END;p<NPAIR;p++) tot+=w[p];
    double acc=0; int c=0;
    for(int p=P1END;p<NPAIR && c<7;p++){ acc+=w[p]; if(acc>=tot*(c+1)/8.0) bnd.e2[c++]=p+1; }
    while(c<7) bnd.e2[c++]=NPAIR;
    bnd.e2[7]=NPAIR;
  }

  main_kernel<<<batch/EPB, TPB, LDS_BYTES, stream>>>(re, im, out, bnd);
}